// Round 1
// baseline (570.482 us; speedup 1.0000x reference)
//
#include <hip/hip_runtime.h>
#include <math.h>

// SSIM loss, (32,3,512,512) fp32, 11x11 sigma=1.5 separable Gaussian, VALID.
// R6 = R5 with the phase-1 issue waste removed (kernel was VALU-issue-bound:
// VALUBusy ~90%, MfmaUtil 0, HBM 10%):
//  - R5 phase 1 ran 296 column-tasks as 8 wave-rounds (each wave: 64 cols,
//    then 10/64 lanes for the tail) = 58% lane utilization. Now:
//      round 1: 4 FULL waves, strip = wave, col = lane (cols 0..63; gc <= 511
//               so no col clamp exists on this path), rows wave-uniform.
//      round 2: wave 0 alone does the 4x10 leftover cols (40 lanes, 1 round).
//    5 wave-rounds instead of 8.
//  - Round-1 row base forced to SGPR via readfirstlane; interior row-blocks
//    (15/16) take a template-specialized clamp-free path -> per-k addressing
//    is SALU (co-issued), v_min gone from the vector path.
//  - finalize folded into the main kernel via done-counter (one less launch).
//  - Phase 2 unchanged from R5: stride-77 scalar b32 reads, 2-way max (free),
//    8 outputs/thread, relu folded into SSIM numerator, one rcp.

#define WIN   11
#define IMG   512
#define OUT_N 502
#define TO_R  32                 // output rows per block
#define TO_C  64                 // output cols per block
#define TI_C  (TO_C + WIN - 1)   // 74 input cols
#define VB_W  77                 // ODD row stride -> conflict-free scalar reads
#define C1F   6.5025f
#define C2F   58.5225f
#define GRID_X 8
#define GRID_Y 16
#define GRID_Z 96
#define NBLOCKS (GRID_X * GRID_Y * GRID_Z)

struct GaussW { float w[WIN]; };

// Vertical 11-tap over 18 input rows -> 8 output rows x 5 fields, one column.
// CR: clamp rows (only last row-block). CC: clamp column (round-2 tail only).
template<bool CR, bool CC>
__device__ __forceinline__ void vert_task(
    const float* __restrict__ Xp, const float* __restrict__ Yp,
    const GaussW& gw, float (*vb)[TO_R][VB_W],
    int r0, int gc, int i0, int c)
{
    if (CC) gc = min(gc, IMG - 1);
    float a0[8] = {0}, a1[8] = {0}, a2[8] = {0}, a3[8] = {0}, a4[8] = {0};
#pragma unroll
    for (int k = 0; k < 18; ++k) {            // 8 outputs need 18 input rows
        int gr = r0 + k;
        if (CR) gr = min(gr, IMG - 1);
        size_t off = (size_t)gr * IMG + gc;   // uniform part scalarizes when
        float x = Xp[off];                    // r0 came from readfirstlane
        float y = Yp[off];
        float xx = x * x, yy = y * y, xy = x * y;
        const int jlo = (k > 10) ? (k - 10) : 0;
        const int jhi = (k < 7) ? k : 7;
#pragma unroll
        for (int j = jlo; j <= jhi; ++j) {
            float wv = gw.w[k - j];
            a0[j] += wv * x;
            a1[j] += wv * y;
            a2[j] += wv * xx;
            a3[j] += wv * yy;
            a4[j] += wv * xy;
        }
    }
#pragma unroll
    for (int j = 0; j < 8; ++j) {             // stride-1 across lanes: free
        int i = i0 + j;
        vb[0][i][c] = a0[j];
        vb[1][i][c] = a1[j];
        vb[2][i][c] = a2[j];
        vb[3][i][c] = a3[j];
        vb[4][i][c] = a4[j];
    }
}

__global__ __launch_bounds__(256) void ssim_v6_kernel(
    const float* __restrict__ X, const float* __restrict__ Y,
    GaussW gw, double* __restrict__ acc, unsigned int* __restrict__ done,
    float* __restrict__ out)
{
    // vertically filtered fields: [field][out_row][col], stride 77
    __shared__ float vb[5][TO_R][VB_W];   // 49280 B -> 3 blocks/CU

    const int plane = blockIdx.z;
    const int ox0 = blockIdx.x * TO_C;    // 64-aligned global columns
    const int oy0 = blockIdx.y * TO_R;
    const float* Xp = X + (size_t)plane * IMG * IMG;
    const float* Yp = Y + (size_t)plane * IMG * IMG;
    const int tid  = threadIdx.x;
    const int wave = tid >> 6;
    const int lane = tid & 63;

    // ---- Phase 1: vertical 11-tap ----
    // Round 1: strip = wave, col = lane. Rows wave-uniform -> SGPR base.
    // gc = ox0 + lane <= 448 + 63 = 511: never needs the col clamp.
    {
        const int r0 = __builtin_amdgcn_readfirstlane(oy0 + wave * 8);
        const int gc = ox0 + lane;
        if (blockIdx.y == GRID_Y - 1)
            vert_task<true,  false>(Xp, Yp, gw, vb, r0, gc, wave * 8, lane);
        else
            vert_task<false, false>(Xp, Yp, gw, vb, r0, gc, wave * 8, lane);
    }
    // Round 2: wave 0 covers the 4 strips x 10 tail cols (c = 64..73).
    // Always fully clamped (40 lanes; clamps are no-ops on interior blocks).
    if (wave == 0 && lane < 40) {
        const int s = lane / 10;              // compiler magic-muls
        const int c = TO_C + (lane - s * 10); // 64..73
        vert_task<true, true>(Xp, Yp, gw, vb, oy0 + s * 8, ox0 + c, s * 8, c);
    }
    __syncthreads();

    // ---- Phase 2: horizontal 11-tap + SSIM, 8 outputs/thread ----
    const int i  = tid >> 3;              // 0..31
    const int c0 = (tid & 7) * 8;         // 0..56
    const int gi = oy0 + i;
    float m[5][8];
#pragma unroll
    for (int f = 0; f < 5; ++f) {
        float v[18];
#pragma unroll
        for (int k = 0; k < 18; ++k) v[k] = vb[f][i][c0 + k];  // b32, 2-way max
#pragma unroll
        for (int oc = 0; oc < 8; ++oc) {
            float s = 0.f;
#pragma unroll
            for (int k = 0; k < WIN; ++k) s += gw.w[k] * v[oc + k];
            m[f][oc] = s;
        }
    }

    float psum = 0.f;
#pragma unroll
    for (int oc = 0; oc < 8; ++oc) {
        int gj = ox0 + c0 + oc;
        if (gi < OUT_N && gj < OUT_N) {
            float m1 = m[0][oc], m2 = m[1][oc];
            float mu1s = m1 * m1, mu2s = m2 * m2, mu12 = m1 * m2;
            float sig1  = m[2][oc] - mu1s;
            float sig2  = m[3][oc] - mu2s;
            float sig12 = m[4][oc] - mu12;
            // ssim = [(2mu12+C1)/(mu1s+mu2s+C1)] * relu[(2sig12+C2)/(sig1+sig2+C2)]
            // first factor and both denominators are > 0 -> relu folds into num.
            float num = (2.f * mu12 + C1F) * (2.f * sig12 + C2F);
            float den = (mu1s + mu2s + C1F) * (sig1 + sig2 + C2F);
            num = fmaxf(num, 0.f);
            psum += num * __builtin_amdgcn_rcpf(den);
        }
    }

    // ---- block reduction + fused finalize ----
#pragma unroll
    for (int off = 32; off > 0; off >>= 1)
        psum += __shfl_down(psum, off, 64);
    __shared__ float wsum[4];
    if ((tid & 63) == 0) wsum[tid >> 6] = psum;
    __syncthreads();
    if (tid == 0) {
        float s = wsum[0] + wsum[1] + wsum[2] + wsum[3];
        atomicAdd(acc, (double)s);            // device-scope by default
        __threadfence();
        unsigned prev = atomicAdd(done, 1u);
        if (prev == NBLOCKS - 1) {            // last block finalizes
            __threadfence();
            double a = atomicAdd(acc, 0.0);   // coherent read of final sum
            const double count = (double)GRID_Z * OUT_N * OUT_N;
            out[0] = (float)(1.0 - a / count);
        }
    }
}

extern "C" void kernel_launch(void* const* d_in, const int* in_sizes, int n_in,
                              void* d_out, int out_size, void* d_ws, size_t ws_size,
                              hipStream_t stream) {
    (void)in_sizes; (void)n_in; (void)out_size; (void)ws_size;
    const float* X = (const float*)d_in[0];
    const float* Y = (const float*)d_in[1];
    float* out = (float*)d_out;
    double* acc = (double*)d_ws;
    unsigned int* done = (unsigned int*)((char*)d_ws + sizeof(double));

    hipMemsetAsync(d_ws, 0, 16, stream);      // acc + done counter

    GaussW gw;
    {
        double g[WIN], s = 0.0;
        for (int i = 0; i < WIN; ++i) {
            double d = (double)(i - 5);
            g[i] = exp(-(d * d) / (2.0 * 1.5 * 1.5));
            s += g[i];
        }
        for (int i = 0; i < WIN; ++i) gw.w[i] = (float)(g[i] / s);
    }

    dim3 grid(GRID_X, GRID_Y, GRID_Z);        // 8 x 16 x 96
    ssim_v6_kernel<<<grid, 256, 0, stream>>>(X, Y, gw, acc, done, out);
}

// Round 2
// 314.206 us; speedup vs baseline: 1.8156x; 1.8156x over previous
//
#include <hip/hip_runtime.h>
#include <math.h>

// SSIM loss, (32,3,512,512) fp32, 11x11 sigma=1.5 separable Gaussian, VALID.
// R7 = R6 minus the fused finalize (single-variable revert).
// R6 post-mortem: VALU-work dropped 157->106 us-equiv exactly as predicted by
// the phase-1 issue restructure, but dur_us went 175->490 with VALUBusy 22%.
// Prime suspect: __threadfence() (agent-scope buffer_wbl2 + buffer_inv, i.e.
// an L2 writeback/invalidate) executed 2x per block x 12288 blocks. Evidence:
// WRITE_SIZE doubled, and L3-resident replay dispatches (hbm~0) were equally
// slow -> stall is residency-independent. R7 restores the separate finalize
// kernel (~3 us) and keeps the phase-1 restructure:
//  - round 1: 4 FULL waves, strip = wave, col = lane (cols 0..63, gc <= 511
//    so no col clamp on this path); row base forced to SGPR via readfirstlane
//    -> per-k addressing is SALU; interior row-blocks (15/16) take a
//    clamp-free template path (no v_min on the vector path).
//  - round 2: wave 0 covers the 4x10 tail cols (40 lanes, 1 wave-round).
//    5 wave-rounds total vs R5's 8.
//  - Phase 2 unchanged: stride-77 scalar b32 LDS reads (2-way max = free),
//    8 outputs/thread, relu folded into SSIM numerator, one rcp.

#define WIN   11
#define IMG   512
#define OUT_N 502
#define TO_R  32                 // output rows per block
#define TO_C  64                 // output cols per block
#define TI_C  (TO_C + WIN - 1)   // 74 input cols
#define VB_W  77                 // ODD row stride -> conflict-free scalar reads
#define C1F   6.5025f
#define C2F   58.5225f
#define GRID_X 8
#define GRID_Y 16
#define GRID_Z 96

struct GaussW { float w[WIN]; };

// Vertical 11-tap over 18 input rows -> 8 output rows x 5 fields, one column.
// CR: clamp rows (only last row-block). CC: clamp column (round-2 tail only).
template<bool CR, bool CC>
__device__ __forceinline__ void vert_task(
    const float* __restrict__ Xp, const float* __restrict__ Yp,
    const GaussW& gw, float (*vb)[TO_R][VB_W],
    int r0, int gc, int i0, int c)
{
    if (CC) gc = min(gc, IMG - 1);
    float a0[8] = {0}, a1[8] = {0}, a2[8] = {0}, a3[8] = {0}, a4[8] = {0};
#pragma unroll
    for (int k = 0; k < 18; ++k) {            // 8 outputs need 18 input rows
        int gr = r0 + k;
        if (CR) gr = min(gr, IMG - 1);
        size_t off = (size_t)gr * IMG + gc;   // uniform part scalarizes when
        float x = Xp[off];                    // r0 came from readfirstlane
        float y = Yp[off];
        float xx = x * x, yy = y * y, xy = x * y;
        const int jlo = (k > 10) ? (k - 10) : 0;
        const int jhi = (k < 7) ? k : 7;
#pragma unroll
        for (int j = jlo; j <= jhi; ++j) {
            float wv = gw.w[k - j];
            a0[j] += wv * x;
            a1[j] += wv * y;
            a2[j] += wv * xx;
            a3[j] += wv * yy;
            a4[j] += wv * xy;
        }
    }
#pragma unroll
    for (int j = 0; j < 8; ++j) {             // stride-1 across lanes: free
        int i = i0 + j;
        vb[0][i][c] = a0[j];
        vb[1][i][c] = a1[j];
        vb[2][i][c] = a2[j];
        vb[3][i][c] = a3[j];
        vb[4][i][c] = a4[j];
    }
}

__global__ __launch_bounds__(256) void ssim_v7_kernel(
    const float* __restrict__ X, const float* __restrict__ Y,
    GaussW gw, double* __restrict__ acc)
{
    // vertically filtered fields: [field][out_row][col], stride 77
    __shared__ float vb[5][TO_R][VB_W];   // 49280 B -> 3 blocks/CU

    const int plane = blockIdx.z;
    const int ox0 = blockIdx.x * TO_C;    // 64-aligned global columns
    const int oy0 = blockIdx.y * TO_R;
    const float* Xp = X + (size_t)plane * IMG * IMG;
    const float* Yp = Y + (size_t)plane * IMG * IMG;
    const int tid  = threadIdx.x;
    const int wave = tid >> 6;
    const int lane = tid & 63;

    // ---- Phase 1: vertical 11-tap ----
    // Round 1: strip = wave, col = lane. Rows wave-uniform -> SGPR base.
    // gc = ox0 + lane <= 448 + 63 = 511: never needs the col clamp.
    {
        const int r0 = __builtin_amdgcn_readfirstlane(oy0 + wave * 8);
        const int gc = ox0 + lane;
        if (blockIdx.y == GRID_Y - 1)
            vert_task<true,  false>(Xp, Yp, gw, vb, r0, gc, wave * 8, lane);
        else
            vert_task<false, false>(Xp, Yp, gw, vb, r0, gc, wave * 8, lane);
    }
    // Round 2: wave 0 covers the 4 strips x 10 tail cols (c = 64..73).
    // Always fully clamped (40 lanes; clamps are no-ops on interior blocks).
    if (wave == 0 && lane < 40) {
        const int s = lane / 10;              // compiler magic-muls
        const int c = TO_C + (lane - s * 10); // 64..73
        vert_task<true, true>(Xp, Yp, gw, vb, oy0 + s * 8, ox0 + c, s * 8, c);
    }
    __syncthreads();

    // ---- Phase 2: horizontal 11-tap + SSIM, 8 outputs/thread ----
    const int i  = tid >> 3;              // 0..31
    const int c0 = (tid & 7) * 8;         // 0..56
    const int gi = oy0 + i;
    float m[5][8];
#pragma unroll
    for (int f = 0; f < 5; ++f) {
        float v[18];
#pragma unroll
        for (int k = 0; k < 18; ++k) v[k] = vb[f][i][c0 + k];  // b32, 2-way max
#pragma unroll
        for (int oc = 0; oc < 8; ++oc) {
            float s = 0.f;
#pragma unroll
            for (int k = 0; k < WIN; ++k) s += gw.w[k] * v[oc + k];
            m[f][oc] = s;
        }
    }

    float psum = 0.f;
#pragma unroll
    for (int oc = 0; oc < 8; ++oc) {
        int gj = ox0 + c0 + oc;
        if (gi < OUT_N && gj < OUT_N) {
            float m1 = m[0][oc], m2 = m[1][oc];
            float mu1s = m1 * m1, mu2s = m2 * m2, mu12 = m1 * m2;
            float sig1  = m[2][oc] - mu1s;
            float sig2  = m[3][oc] - mu2s;
            float sig12 = m[4][oc] - mu12;
            // ssim = [(2mu12+C1)/(mu1s+mu2s+C1)] * relu[(2sig12+C2)/(sig1+sig2+C2)]
            // first factor and both denominators are > 0 -> relu folds into num.
            float num = (2.f * mu12 + C1F) * (2.f * sig12 + C2F);
            float den = (mu1s + mu2s + C1F) * (sig1 + sig2 + C2F);
            num = fmaxf(num, 0.f);
            psum += num * __builtin_amdgcn_rcpf(den);
        }
    }

    // ---- block reduction ----
#pragma unroll
    for (int off = 32; off > 0; off >>= 1)
        psum += __shfl_down(psum, off, 64);
    __shared__ float wsum[4];
    if ((tid & 63) == 0) wsum[tid >> 6] = psum;
    __syncthreads();
    if (tid == 0) {
        float s = wsum[0] + wsum[1] + wsum[2] + wsum[3];
        atomicAdd(acc, (double)s);            // device-scope by default
    }
}

__global__ void ssim_finalize_kernel(const double* __restrict__ acc,
                                     float* __restrict__ out)
{
    if (threadIdx.x == 0 && blockIdx.x == 0) {
        const double count = (double)GRID_Z * OUT_N * OUT_N;
        out[0] = (float)(1.0 - (*acc) / count);
    }
}

extern "C" void kernel_launch(void* const* d_in, const int* in_sizes, int n_in,
                              void* d_out, int out_size, void* d_ws, size_t ws_size,
                              hipStream_t stream) {
    (void)in_sizes; (void)n_in; (void)out_size; (void)ws_size;
    const float* X = (const float*)d_in[0];
    const float* Y = (const float*)d_in[1];
    float* out = (float*)d_out;
    double* acc = (double*)d_ws;

    hipMemsetAsync(d_ws, 0, sizeof(double), stream);

    GaussW gw;
    {
        double g[WIN], s = 0.0;
        for (int i = 0; i < WIN; ++i) {
            double d = (double)(i - 5);
            g[i] = exp(-(d * d) / (2.0 * 1.5 * 1.5));
            s += g[i];
        }
        for (int i = 0; i < WIN; ++i) gw.w[i] = (float)(g[i] / s);
    }

    dim3 grid(GRID_X, GRID_Y, GRID_Z);        // 8 x 16 x 96
    ssim_v7_kernel<<<grid, 256, 0, stream>>>(X, Y, gw, acc);
    ssim_finalize_kernel<<<1, 64, 0, stream>>>(acc, out);
}